// Round 5
// baseline (110.776 us; speedup 1.0000x reference)
//
#include <hip/hip_runtime.h>

typedef __attribute__((ext_vector_type(8))) short bf16x8;
typedef __attribute__((ext_vector_type(4))) float f32x4;
typedef __attribute__((ext_vector_type(2))) unsigned int u32x2;
typedef __attribute__((ext_vector_type(4))) unsigned int u32x4;

__device__ __forceinline__ unsigned short f2bf(float f) {
  return __builtin_bit_cast(unsigned short, (__bf16)f);
}
__device__ __forceinline__ unsigned pk2(float a, float b) {
  return (unsigned)f2bf(a) | ((unsigned)f2bf(b) << 16);
}
__device__ __forceinline__ bf16x8 frag(u32x4 v) { return __builtin_bit_cast(bf16x8, v); }

// wave-level compiler memory fence (cross-lane LDS handoff within a wave)
__device__ __forceinline__ void wfence() {
  asm volatile("" ::: "memory");
  __builtin_amdgcn_wave_barrier();
}

#define MFMA16(a, b, c) __builtin_amdgcn_mfma_f32_16x16x32_bf16(a, b, c, 0, 0, 0)

#define LR 72            // 64-col rows, 144 B stride: 16B-aligned, bank-rotating
#define OFF_VT 4608      // K: rows 0..63 at 0;  VT: rows 0..63 at 4608
#define ZOK 64           // 16B zero block in K row-0 padding
#define LDS_TOT 9216     // ushorts = 18,432 B -> LDS allows 8 blocks/CU

// ---- weight prep ----
// pi k-permutation: slot(ks,g,j) -> source col 16*(2ks + (j>>2)) + 4g + (j&3).
// Producers of activations leave cols {16mt+4g+r} lane-resident; consuming
// MFMAs use weights prepped with pi on the k-dim so B-operand = producer regs.
// chunks (1 KB each): [0,8)=WqT(pi, x0.125*log2e) [8,16)=WkT(pi) [16,24)=Wv(pi)
// [24,32)=WpT(natural) [32,64)=W1T(pi) [64,96)=W2T(pi per 64-chunk)
__global__ void prep_weights(const float* __restrict__ wq, const float* __restrict__ wk,
                             const float* __restrict__ wv, const float* __restrict__ projw,
                             const float* __restrict__ fc1w, const float* __restrict__ fc2w,
                             unsigned short* __restrict__ ws) {
  int c = blockIdx.x, l = threadIdx.x;
  int g = l >> 4, jl = l & 15;
  int kind, T, ks;
  if (c < 8)       { kind = 0; T = c >> 1;        ks = c & 1; }
  else if (c < 16) { kind = 1; T = (c - 8) >> 1;  ks = (c - 8) & 1; }
  else if (c < 24) { kind = 2; T = (c - 16) >> 1; ks = (c - 16) & 1; }
  else if (c < 32) { kind = 3; T = (c - 24) >> 1; ks = (c - 24) & 1; }
  else if (c < 64) { kind = 4; T = (c - 32) >> 1; ks = (c - 32) & 1; }
  else             { kind = 5; T = (c - 64) >> 3; ks = (c - 64) & 7; }
  int n = 16 * T + jl;
  unsigned short* dst = ws + c * 512 + l * 8;
  #pragma unroll
  for (int jj = 0; jj < 8; ++jj) {
    int kp = 16 * (2 * (ks & 1) + (jj >> 2)) + 4 * g + (jj & 3);   // pi slot->col
    int kn = 32 * ks + 8 * g + jj;                                  // natural
    float v;
    if (kind == 0)      v = wq[(n >> 3) * 512 + kp * 8 + (n & 7)] * 0.18033688011f;
    else if (kind == 1) v = wk[(n >> 3) * 512 + kp * 8 + (n & 7)];
    else if (kind == 2) v = wv[(n >> 3) * 512 + kp * 8 + (n & 7)];
    else if (kind == 3) v = projw[kn * 64 + n];
    else if (kind == 4) v = fc1w[kp * 256 + n];
    else                v = fc2w[(64 * (ks >> 1) + kp) * 64 + n];
    dst[jj] = f2bf(v);
  }
}

__global__ __launch_bounds__(256, 6) void block_fused(
    const float* __restrict__ x,
    const float* __restrict__ ln1w, const float* __restrict__ ln1b,
    const float* __restrict__ projb,
    const float* __restrict__ ln2w, const float* __restrict__ ln2b,
    const float* __restrict__ fc1b, const float* __restrict__ fc2b,
    const unsigned short* __restrict__ wsm, float* __restrict__ out) {
  __shared__ __attribute__((aligned(16))) unsigned short lds[LDS_TOT];

  const int tid  = threadIdx.x;
  const int w    = tid >> 6;     // wave 0..3 owns tokens 16w..16w+15
  const int lane = tid & 63;
  const int g    = lane >> 4;
  const int jl   = lane & 15;
  const size_t b = blockIdx.x;
  const float* xb = x + b * 4096;
  const f32x4 zf = {0.f, 0.f, 0.f, 0.f};
  const bf16x8 z8 = {0, 0, 0, 0, 0, 0, 0, 0};

  const int myrow = 16 * w + jl;                 // this lane's token
  const int krow  = myrow * LR;                  // K region row (base 0)
  const int sigb  = 32 * (w >> 1) + 8 * g + 4 * (w & 1);  // sigma slot base for V stores

  // ---------- LN1 fully in registers (token = myrow; reduce over g via shfl) ----------
  f32x4 xw[4];
  float mean, rstd;
  {
    float s = 0.f, ss = 0.f;
    #pragma unroll
    for (int mi = 0; mi < 4; ++mi) {
      xw[mi] = *(const f32x4*)(xb + myrow * 64 + 16 * mi + 4 * g);
      #pragma unroll
      for (int r = 0; r < 4; ++r) { s += xw[mi][r]; ss += xw[mi][r] * xw[mi][r]; }
    }
    s  += __shfl_xor(s, 16, 64);  s  += __shfl_xor(s, 32, 64);
    ss += __shfl_xor(ss, 16, 64); ss += __shfl_xor(ss, 32, 64);
    mean = s * 0.015625f;
    rstd = rsqrtf(ss * 0.015625f - mean * mean + 1e-5f);
  }
  unsigned hr[8];
  #pragma unroll
  for (int mi = 0; mi < 4; ++mi) {
    f32x4 lw = *(const f32x4*)(ln1w + 16 * mi + 4 * g);
    f32x4 lb = *(const f32x4*)(ln1b + 16 * mi + 4 * g);
    float o0 = (xw[mi][0] - mean) * rstd * lw[0] + lb[0];
    float o1 = (xw[mi][1] - mean) * rstd * lw[1] + lb[1];
    float o2 = (xw[mi][2] - mean) * rstd * lw[2] + lb[2];
    float o3 = (xw[mi][3] - mean) * rstd * lw[3] + lb[3];
    hr[2 * mi] = pk2(o0, o1); hr[2 * mi + 1] = pk2(o2, o3);
  }
  bf16x8 hb0 = frag((u32x4){hr[0], hr[1], hr[2], hr[3]});   // pi-layout B-frag ks=0
  bf16x8 hb1 = frag((u32x4){hr[4], hr[5], hr[6], hr[7]});   // ks=1

  // ---------- QKV: Q->regs, K->LDS (natural rows), V->LDS VT (sigma slots) ----------
  unsigned Uq[8];
  #pragma unroll
  for (int mt = 0; mt < 4; ++mt) {
    bf16x8 aq0 = *(const bf16x8*)(wsm + (0 + 2 * mt) * 512 + lane * 8);
    bf16x8 aq1 = *(const bf16x8*)(wsm + (1 + 2 * mt) * 512 + lane * 8);
    f32x4 q = MFMA16(aq0, hb0, zf); q = MFMA16(aq1, hb1, q);
    Uq[2 * mt] = pk2(q[0], q[1]); Uq[2 * mt + 1] = pk2(q[2], q[3]);

    bf16x8 ak0 = *(const bf16x8*)(wsm + (8 + 2 * mt) * 512 + lane * 8);
    bf16x8 ak1 = *(const bf16x8*)(wsm + (9 + 2 * mt) * 512 + lane * 8);
    f32x4 kk = MFMA16(ak0, hb0, zf); kk = MFMA16(ak1, hb1, kk);
    *(u32x2*)(lds + krow + 16 * mt + 4 * g) = (u32x2){pk2(kk[0], kk[1]), pk2(kk[2], kk[3])};

    // V non-swapped: A = own H regs (pi), B = Wv chunk -> lane holds V[16w+4g+r][16mt+jl]
    bf16x8 bv0 = *(const bf16x8*)(wsm + (16 + 2 * mt) * 512 + lane * 8);
    bf16x8 bv1 = *(const bf16x8*)(wsm + (17 + 2 * mt) * 512 + lane * 8);
    f32x4 vv = MFMA16(hb0, bv0, zf); vv = MFMA16(hb1, bv1, vv);
    *(u32x2*)(lds + OFF_VT + (16 * mt + jl) * LR + sigb) =
        (u32x2){pk2(vv[0], vv[1]), pk2(vv[2], vv[3])};
  }
  if (tid == 0) *(u32x4*)(lds + ZOK) = (u32x4){0u, 0u, 0u, 0u};
  __syncthreads();   // barrier 1: publish K, VT

  // ---------- attention: S^T=mfma(K,Q); lane-local softmax; PV from regs ----------
  unsigned at0[8], at1[8];
  #pragma unroll
  for (int h = 0; h < 8; ++h) {
    const int mt = h >> 1, a = 2 * (h & 1);
    unsigned q0 = __shfl(Uq[2 * mt],     16 * a + jl, 64);
    unsigned q1 = __shfl(Uq[2 * mt + 1], 16 * a + jl, 64);
    unsigned q2 = __shfl(Uq[2 * mt],     16 * a + 16 + jl, 64);
    unsigned q3 = __shfl(Uq[2 * mt + 1], 16 * a + 16 + jl, 64);
    bf16x8 bq = (g == 0) ? frag((u32x4){q0, q1, q2, q3}) : z8;
    unsigned Up[8];
    float sum = 0.f;
    #pragma unroll
    for (int mi = 0; mi < 4; ++mi) {
      if (mi <= w) {   // wave-uniform causal tile skip
        bf16x8 ak = *(const bf16x8*)(lds + ((g == 0) ? ((16 * mi + jl) * LR + 8 * h) : ZOK));
        f32x4 sc = MFMA16(ak, bq, zf);
        float e0 = exp2f(sc[0]), e1 = exp2f(sc[1]);
        float e2 = exp2f(sc[2]), e3 = exp2f(sc[3]);
        if (mi == w) {   // diagonal: keep s<=q  <=>  4g+r <= jl
          e0 = (4 * g + 0 <= jl) ? e0 : 0.f;
          e1 = (4 * g + 1 <= jl) ? e1 : 0.f;
          e2 = (4 * g + 2 <= jl) ? e2 : 0.f;
          e3 = (4 * g + 3 <= jl) ? e3 : 0.f;
        }
        sum += (e0 + e1) + (e2 + e3);
        Up[2 * mi] = pk2(e0, e1); Up[2 * mi + 1] = pk2(e2, e3);
      } else { Up[2 * mi] = 0u; Up[2 * mi + 1] = 0u; }
    }
    sum += __shfl_xor(sum, 16, 64);
    sum += __shfl_xor(sum, 32, 64);
    float inv = __builtin_amdgcn_rcpf(sum);
    bf16x8 bp0 = frag((u32x4){Up[0], Up[1], Up[2], Up[3]});   // pi-slots = sigma tokens
    bf16x8 bp1 = frag((u32x4){Up[4], Up[5], Up[6], Up[7]});
    const int vtr = OFF_VT + (8 * h + jl) * LR;
    bf16x8 aw0 = *(const bf16x8*)(lds + ((jl < 8) ? (vtr + 8 * g) : ZOK));
    bf16x8 aw1 = *(const bf16x8*)(lds + ((jl < 8) ? (vtr + 32 + 8 * g) : ZOK));
    f32x4 pv = MFMA16(aw0, bp0, zf); pv = MFMA16(aw1, bp1, pv);
    at0[h] = pk2(pv[0] * inv, pv[1] * inv);   // d = 8h+4g+{0..3}, valid g<2
    at1[h] = pk2(pv[2] * inv, pv[3] * inv);
  }
  __syncthreads();   // barrier 2: all waves done reading K/VT
  if (g < 2) {       // dump attn rows into dead K region (natural col order)
    #pragma unroll
    for (int h = 0; h < 8; ++h)
      *(u32x2*)(lds + krow + 8 * h + 4 * g) = (u32x2){at0[h], at1[h]};
  }
  wfence();
  bf16x8 bat0 = *(const bf16x8*)(lds + krow + 8 * g);
  bf16x8 bat1 = *(const bf16x8*)(lds + krow + 32 + 8 * g);

  // ---------- proj (swapped, natural k) + residual; x2 in fp32 regs ----------
  f32x4 x2[4];
  #pragma unroll
  for (int mi = 0; mi < 4; ++mi) {
    bf16x8 a0 = *(const bf16x8*)(wsm + (24 + 2 * mi) * 512 + lane * 8);
    bf16x8 a1 = *(const bf16x8*)(wsm + (25 + 2 * mi) * 512 + lane * 8);
    f32x4 acc = MFMA16(a0, bat0, zf); acc = MFMA16(a1, bat1, acc);
    f32x4 xv = *(const f32x4*)(xb + myrow * 64 + 16 * mi + 4 * g);
    f32x4 pb = *(const f32x4*)(projb + 16 * mi + 4 * g);
    x2[mi] = xv + acc + pb;
  }

  // ---------- LN2 in registers ----------
  float mean2, rstd2;
  {
    float s = 0.f, ss = 0.f;
    #pragma unroll
    for (int mi = 0; mi < 4; ++mi)
      #pragma unroll
      for (int r = 0; r < 4; ++r) { s += x2[mi][r]; ss += x2[mi][r] * x2[mi][r]; }
    s  += __shfl_xor(s, 16, 64);  s  += __shfl_xor(s, 32, 64);
    ss += __shfl_xor(ss, 16, 64); ss += __shfl_xor(ss, 32, 64);
    mean2 = s * 0.015625f;
    rstd2 = rsqrtf(ss * 0.015625f - mean2 * mean2 + 1e-5f);
  }
  unsigned h2[8];
  #pragma unroll
  for (int mi = 0; mi < 4; ++mi) {
    f32x4 lw = *(const f32x4*)(ln2w + 16 * mi + 4 * g);
    f32x4 lb = *(const f32x4*)(ln2b + 16 * mi + 4 * g);
    float o0 = (x2[mi][0] - mean2) * rstd2 * lw[0] + lb[0];
    float o1 = (x2[mi][1] - mean2) * rstd2 * lw[1] + lb[1];
    float o2 = (x2[mi][2] - mean2) * rstd2 * lw[2] + lb[2];
    float o3 = (x2[mi][3] - mean2) * rstd2 * lw[3] + lb[3];
    h2[2 * mi] = pk2(o0, o1); h2[2 * mi + 1] = pk2(o2, o3);
  }
  bf16x8 hc0 = frag((u32x4){h2[0], h2[1], h2[2], h2[3]});
  bf16x8 hc1 = frag((u32x4){h2[4], h2[5], h2[6], h2[7]});

  // ---------- FF: fc1 (pi) -> relu regs -> fc2 (pi per 64-chunk), all registers ----------
  f32x4 acc2[4];
  #pragma unroll
  for (int mi = 0; mi < 4; ++mi) acc2[mi] = zf;
  #pragma unroll
  for (int c = 0; c < 4; ++c) {
    unsigned fr[8];
    #pragma unroll
    for (int ml = 0; ml < 4; ++ml) {
      int T = 4 * c + ml;
      bf16x8 a0 = *(const bf16x8*)(wsm + (32 + 2 * T) * 512 + lane * 8);
      bf16x8 a1 = *(const bf16x8*)(wsm + (33 + 2 * T) * 512 + lane * 8);
      f32x4 acc = MFMA16(a0, hc0, zf); acc = MFMA16(a1, hc1, acc);
      f32x4 bb = *(const f32x4*)(fc1b + 16 * T + 4 * g);
      float r0 = fmaxf(acc[0] + bb[0], 0.f), r1 = fmaxf(acc[1] + bb[1], 0.f);
      float r2 = fmaxf(acc[2] + bb[2], 0.f), r3 = fmaxf(acc[3] + bb[3], 0.f);
      fr[2 * ml] = pk2(r0, r1); fr[2 * ml + 1] = pk2(r2, r3);
    }
    bf16x8 bf0 = frag((u32x4){fr[0], fr[1], fr[2], fr[3]});
    bf16x8 bf1 = frag((u32x4){fr[4], fr[5], fr[6], fr[7]});
    #pragma unroll
    for (int mi = 0; mi < 4; ++mi) {
      bf16x8 w20 = *(const bf16x8*)(wsm + (64 + 8 * mi + 2 * c) * 512 + lane * 8);
      bf16x8 w21 = *(const bf16x8*)(wsm + (65 + 8 * mi + 2 * c) * 512 + lane * 8);
      acc2[mi] = MFMA16(w20, bf0, acc2[mi]);
      acc2[mi] = MFMA16(w21, bf1, acc2[mi]);
    }
  }

  // ---------- epilogue ----------
  {
    float* ob = out + b * 4096 + myrow * 64;
    #pragma unroll
    for (int mi = 0; mi < 4; ++mi) {
      f32x4 fb = *(const f32x4*)(fc2b + 16 * mi + 4 * g);
      f32x4 o = x2[mi] + acc2[mi] + fb;
      *(f32x4*)(ob + 16 * mi + 4 * g) = o;
    }
  }
}

extern "C" void kernel_launch(void* const* d_in, const int* in_sizes, int n_in,
                              void* d_out, int out_size, void* d_ws, size_t ws_size,
                              hipStream_t stream) {
  const float* x     = (const float*)d_in[0];
  const float* ln1w  = (const float*)d_in[1];
  const float* ln1b  = (const float*)d_in[2];
  const float* wq    = (const float*)d_in[3];
  const float* wk    = (const float*)d_in[4];
  const float* wvp   = (const float*)d_in[5];
  const float* projw = (const float*)d_in[6];
  const float* projb = (const float*)d_in[7];
  const float* ln2w  = (const float*)d_in[8];
  const float* ln2b  = (const float*)d_in[9];
  const float* fc1w  = (const float*)d_in[10];
  const float* fc1b  = (const float*)d_in[11];
  const float* fc2w  = (const float*)d_in[12];
  const float* fc2b  = (const float*)d_in[13];
  unsigned short* ws = (unsigned short*)d_ws;   // 96 KB repacked weights
  float* out = (float*)d_out;

  prep_weights<<<dim3(96), dim3(64), 0, stream>>>(wq, wk, wvp, projw, fc1w, fc2w, ws);

  int nblk = in_sizes[0] / 4096;
  block_fused<<<dim3(nblk), dim3(256), 0, stream>>>(
      x, ln1w, ln1b, projb, ln2w, ln2b, fc1b, fc2b, ws, out);
}